// Round 2
// baseline (253.658 us; speedup 1.0000x reference)
//
#include <hip/hip_runtime.h>
#include <hip/hip_fp16.h>

#define NMOL   32
#define NATOM  512
#define NPAIR  32768
#define NB     64
#define HIDDEN 256
#define TOTNATOM (NMOL * NATOM)
#define CAP    192   // stage capacity per wave (drain when base > 128)

// process one compacted pair (broadcast scalars) for this lane's basis
__device__ __forceinline__ void do_pair(unsigned dfp, unsigned pk, float cb, float wb,
                                        const float* __restrict__ cemb,
                                        float* __restrict__ dens, int lane) {
    __half2 hh = *reinterpret_cast<const __half2*>(&dfp);
    const float bd  = __low2float(hh);    // distance
    const float bfc = __high2float(hh);   // fc (0 for pad entries)
    const float ce  = cemb[(pk & 7u) * NB + lane];
    const float t   = bd - cb;
    atomicAdd(&dens[(int)(pk >> 3) * NB + lane], __expf(-wb * t * t) * bfc * ce);
}

// ---------------------------------------------------------------------------
// pair_kernel: grid = 32 mol x 8 slices, 1024 threads (16 waves)
// phase 1 (lane=pair): dist/cutoff + tv atomics + ballot-compact staging
// phase 2 (lane=basis): counted drain loop, broadcast LDS reads, pipelined x4
// ---------------------------------------------------------------------------
__global__ __launch_bounds__(1024) void pair_kernel(
    const float* __restrict__ cart, const float* __restrict__ shifts,
    const float* __restrict__ centers, const float* __restrict__ widths,
    const float* __restrict__ c_emb, const int* __restrict__ species,
    const int* __restrict__ atom_index,
    float* __restrict__ density_g, float* __restrict__ totvec_g)
{
    __shared__ float dens[NATOM * NB];                       // 128 KB
    __shared__ float tv[NATOM * 3];                          // 6 KB
    __shared__ float cemb[8 * NB];                           // 2 KB
    __shared__ __align__(16) unsigned       s_df[16][CAP + 4]; // 12.25 KB
    __shared__ __align__(8)  unsigned short s_pk[16][CAP + 4]; // 6.1 KB

    const int tid = threadIdx.x;
    const int mol = blockIdx.x >> 3;
    const int sub = blockIdx.x & 7;

    {
        float4 z = make_float4(0.f, 0.f, 0.f, 0.f);
        float4* d4 = reinterpret_cast<float4*>(dens);
        for (int i = tid; i < NATOM * NB / 4; i += 1024) d4[i] = z;
        for (int i = tid; i < NATOM * 3;  i += 1024) tv[i] = 0.f;
        if (tid < 8 * NB) cemb[tid] = c_emb[tid];
    }
    __syncthreads();

    const int lane = tid & 63;
    const int wave = tid >> 6;
    const float cb = centers[lane];   // lane = basis index in phase 2
    const float wb = widths[lane];

    const int*   ai0 = atom_index + (size_t)mol * NPAIR;
    const int*   ai1 = ai0 + (size_t)NMOL * NPAIR;
    const float* sh  = shifts + (size_t)mol * NPAIR * 3;
    const float* cm  = cart + (size_t)mol * NATOM * 3;
    const int*   sp  = species + (size_t)mol * NATOM;

    const int pbase = sub * 4096 + wave * 256;
    int base = 0;

    for (int it = 0; it < 4; ++it) {
        const int p  = pbase + it * 64 + lane;   // lane = pair (phase 1)
        const int i0 = ai0[p];
        const int i1 = ai1[p];
        const float sx = sh[p * 3 + 0], sy = sh[p * 3 + 1], sz = sh[p * 3 + 2];
        const float m = (sx > -1e10f && sy > -1e10f && sz > -1e10f) ? 1.f : 0.f;
        const float dx = (cm[i0 * 3 + 0] - cm[i1 * 3 + 0] + sx) * m;
        const float dy = (cm[i0 * 3 + 1] - cm[i1 * 3 + 1] + sy) * m;
        const float dz = (cm[i0 * 3 + 2] - cm[i1 * 3 + 2] + sz) * m;
        const float d = sqrtf(dx * dx + dy * dy + dz * dz + 1e-12f);
        float fc = 0.f;
        if (d < 5.0f)
            fc = 0.5f * (__cosf(0.62831853071795864769f * d) + 1.f) * m;  // pi/RC

        // tot_vec segment-sum (all valid pairs, independent of cutoff)
        atomicAdd(&tv[i0 * 3 + 0], dx);
        atomicAdd(&tv[i0 * 3 + 1], dy);
        atomicAdd(&tv[i0 * 3 + 2], dz);

        // ballot-compact the in-cutoff pairs into per-wave staging
        const unsigned long long mask = __ballot(fc > 0.f);
        const int pos = __builtin_amdgcn_mbcnt_hi((unsigned)(mask >> 32),
                        __builtin_amdgcn_mbcnt_lo((unsigned)mask, 0u));
        if (fc > 0.f) {
            __half2 hh = __floats2half2_rn(d, fc);
            s_df[wave][base + pos] = *reinterpret_cast<unsigned*>(&hh);
            s_pk[wave][base + pos] = (unsigned short)((i0 << 3) | sp[i1]);
        }
        base += __popcll(mask);

        // drain (counted loop, unroll x4, broadcast b128/b64 LDS reads)
        if (it == 3 || base > 128) {
            if (lane < 4) { s_df[wave][base + lane] = 0u; s_pk[wave][base + lane] = 0; }
            for (int k = 0; k < base; k += 4) {
                const uint4   df4 = *reinterpret_cast<const uint4*>(&s_df[wave][k]);
                const ushort4 pk4 = *reinterpret_cast<const ushort4*>(&s_pk[wave][k]);
                do_pair(df4.x, pk4.x, cb, wb, cemb, dens, lane);
                do_pair(df4.y, pk4.y, cb, wb, cemb, dens, lane);
                do_pair(df4.z, pk4.z, cb, wb, cemb, dens, lane);
                do_pair(df4.w, pk4.w, cb, wb, cemb, dens, lane);
            }
            base = 0;
        }
    }
    __syncthreads();

    // flush partial molecule density/tot_vec to global (8 blocks contend)
    float* dg = density_g + (size_t)mol * NATOM * NB;
    for (int i = tid * 4; i < NATOM * NB; i += 4096) {
        const float4 v = *reinterpret_cast<const float4*>(&dens[i]);
        unsafeAtomicAdd(&dg[i + 0], v.x);
        unsafeAtomicAdd(&dg[i + 1], v.y);
        unsafeAtomicAdd(&dg[i + 2], v.z);
        unsafeAtomicAdd(&dg[i + 3], v.w);
    }
    float* tg = totvec_g + (size_t)mol * NATOM * 3;
    for (int i = tid; i < NATOM * 3; i += 1024) unsafeAtomicAdd(&tg[i], tv[i]);
}

// ---------------------------------------------------------------------------
// nn_kernel: 1024 blocks x 256 threads; block = 16 atoms, thread = hidden unit
// density rows are block-uniform (scalar loads); 16 independent FMA chains
// ---------------------------------------------------------------------------
__global__ __launch_bounds__(256) void nn_kernel(
    const float* __restrict__ density, const float* __restrict__ totvec,
    const float* __restrict__ W1, const float* __restrict__ b1,
    const float* __restrict__ W2, const float* __restrict__ b2,
    float* __restrict__ dipole)
{
    const int j    = threadIdx.x;       // hidden unit 0..255
    const int lane = j & 63;
    const int wave = j >> 6;
    const int a0   = blockIdx.x * 16;

    float w1r[64];
#pragma unroll
    for (int b = 0; b < 64; ++b) w1r[b] = W1[b * HIDDEN + j];
    const float b1v = b1[j];
    const float w2v = W2[j];

    float con[16];
#pragma unroll
    for (int a = 0; a < 16; ++a) {
        const float* row = density + (size_t)(a0 + a) * NB;   // uniform -> s_load
        float h0 = b1v, h1 = 0.f, h2 = 0.f, h3 = 0.f;
#pragma unroll
        for (int b = 0; b < 64; b += 4) {
            h0 = fmaf(row[b + 0], w1r[b + 0], h0);
            h1 = fmaf(row[b + 1], w1r[b + 1], h1);
            h2 = fmaf(row[b + 2], w1r[b + 2], h2);
            h3 = fmaf(row[b + 3], w1r[b + 3], h3);
        }
        const float h = (h0 + h1) + (h2 + h3);
        con[a] = (h / (1.f + __expf(-h))) * w2v;              // silu * W2
    }

    __shared__ float part[4][16];
#pragma unroll
    for (int a = 0; a < 16; ++a) {
        float v = con[a];
#pragma unroll
        for (int off = 32; off; off >>= 1) v += __shfl_down(v, off);
        if (lane == 0) part[wave][a] = v;
    }
    __syncthreads();

    if (j < 16) {
        const int a = j;
        const float out = part[0][a] + part[1][a] + part[2][a] + part[3][a] + b2[0];
        const float* tvp = totvec + (size_t)(a0 + a) * 3;
        float px = out * tvp[0], py = out * tvp[1], pz = out * tvp[2];
#pragma unroll
        for (int off = 8; off; off >>= 1) {
            px += __shfl_down(px, off, 16);
            py += __shfl_down(py, off, 16);
            pz += __shfl_down(pz, off, 16);
        }
        if (a == 0) {
            const int m = blockIdx.x >> 5;   // 32 blocks per molecule
            unsafeAtomicAdd(&dipole[m * 3 + 0], px);
            unsafeAtomicAdd(&dipole[m * 3 + 1], py);
            unsafeAtomicAdd(&dipole[m * 3 + 2], pz);
        }
    }
}

// ---------------------------------------------------------------------------
extern "C" void kernel_launch(void* const* d_in, const int* in_sizes, int n_in,
                              void* d_out, int out_size, void* d_ws, size_t ws_size,
                              hipStream_t stream)
{
    const float* cart       = (const float*)d_in[0];
    const float* shifts     = (const float*)d_in[1];
    const float* centers    = (const float*)d_in[2];
    const float* widths     = (const float*)d_in[3];
    const float* c_emb      = (const float*)d_in[4];
    const float* W1         = (const float*)d_in[5];
    const float* b1         = (const float*)d_in[6];
    const float* W2         = (const float*)d_in[7];
    const float* b2         = (const float*)d_in[8];
    const int*   species    = (const int*)d_in[10];
    const int*   atom_index = (const int*)d_in[11];

    float* density = (float*)d_ws;                       // [TOTNATOM][64]  4 MB
    float* totvec  = density + (size_t)TOTNATOM * NB;    // [TOTNATOM][3]   192 KB
    float* dipole  = (float*)d_out;                      // [32][3]

    const size_t zero_bytes = ((size_t)TOTNATOM * NB + (size_t)TOTNATOM * 3) * sizeof(float);
    hipMemsetAsync(d_ws, 0, zero_bytes, stream);
    hipMemsetAsync(d_out, 0, (size_t)out_size * sizeof(float), stream);

    hipLaunchKernelGGL(pair_kernel, dim3(NMOL * 8), dim3(1024), 0, stream,
                       cart, shifts, centers, widths, c_emb, species, atom_index,
                       density, totvec);
    hipLaunchKernelGGL(nn_kernel, dim3(TOTNATOM / 16), dim3(256), 0, stream,
                       density, totvec, W1, b1, W2, b2, dipole);
}

// Round 3
// 176.095 us; speedup vs baseline: 1.4405x; 1.4405x over previous
//
#include <hip/hip_runtime.h>
#include <hip/hip_fp16.h>

#define NMOL   32
#define NATOM  512
#define NPAIR  32768
#define NB     64
#define HIDDEN 256
#define TOTNATOM (NMOL * NATOM)
#define CAP    192   // stage capacity per wave (drain when base > 128)

__device__ __forceinline__ void do_pair(unsigned dfp, unsigned pk, float cb, float wb,
                                        const float* __restrict__ cemb,
                                        float* __restrict__ dens, int lane) {
    __half2 hh = *reinterpret_cast<const __half2*>(&dfp);
    const float bd  = __low2float(hh);    // distance
    const float bfc = __high2float(hh);   // fc (0 for pad entries)
    const float ce  = cemb[(pk & 7u) * NB + lane];
    const float t   = bd - cb;
    atomicAdd(&dens[(int)(pk >> 3) * NB + lane], __expf(-wb * t * t) * bfc * ce);
}

// ---------------------------------------------------------------------------
// pair_kernel: grid = NMOL * nsub blocks, 1024 threads (16 waves)
// phase 1 (lane=pair): dist/cutoff + tv LDS atomics + ballot-compact staging
// phase 2 (lane=basis): counted drain loop, broadcast LDS reads
// flush: PLAIN coalesced stores to a private per-block partial region (no
//        global atomics -- those serialized at the coherence point, 90% of
//        rounds 1-2's pair time)
// ---------------------------------------------------------------------------
__global__ __launch_bounds__(1024) void pair_kernel(
    const float* __restrict__ cart, const float* __restrict__ shifts,
    const float* __restrict__ centers, const float* __restrict__ widths,
    const float* __restrict__ c_emb, const int* __restrict__ species,
    const int* __restrict__ atom_index,
    float* __restrict__ dens_part, float* __restrict__ tv_part, int nsub)
{
    __shared__ float dens[NATOM * NB];                         // 128 KB
    __shared__ float tv[NATOM * 3];                            // 6 KB
    __shared__ float cemb[8 * NB];                             // 2 KB
    __shared__ __align__(16) unsigned       s_df[16][CAP + 4]; // 12.25 KB
    __shared__ __align__(8)  unsigned short s_pk[16][CAP + 4]; // 6.1 KB

    const int tid = threadIdx.x;
    const int mol = blockIdx.x / nsub;
    const int sub = blockIdx.x % nsub;

    {
        float4 z = make_float4(0.f, 0.f, 0.f, 0.f);
        float4* d4 = reinterpret_cast<float4*>(dens);
        for (int i = tid; i < NATOM * NB / 4; i += 1024) d4[i] = z;
        for (int i = tid; i < NATOM * 3;  i += 1024) tv[i] = 0.f;
        if (tid < 8 * NB) cemb[tid] = c_emb[tid];
    }
    __syncthreads();

    const int lane = tid & 63;
    const int wave = tid >> 6;
    const float cb = centers[lane];   // lane = basis index in phase 2
    const float wb = widths[lane];

    const int*   ai0 = atom_index + (size_t)mol * NPAIR;
    const int*   ai1 = ai0 + (size_t)NMOL * NPAIR;
    const float* sh  = shifts + (size_t)mol * NPAIR * 3;
    const float* cm  = cart + (size_t)mol * NATOM * 3;
    const int*   sp  = species + (size_t)mol * NATOM;

    const int ppb  = NPAIR / nsub;          // pairs per block
    const int its  = ppb / 1024;            // phase-1 iterations
    const int pbase = sub * ppb + wave * (ppb >> 4);
    int base = 0;

    for (int it = 0; it < its; ++it) {
        const int p  = pbase + it * 64 + lane;   // lane = pair (phase 1)
        const int i0 = ai0[p];
        const int i1 = ai1[p];
        const float sx = sh[p * 3 + 0], sy = sh[p * 3 + 1], sz = sh[p * 3 + 2];
        const float m = (sx > -1e10f && sy > -1e10f && sz > -1e10f) ? 1.f : 0.f;
        const float dx = (cm[i0 * 3 + 0] - cm[i1 * 3 + 0] + sx) * m;
        const float dy = (cm[i0 * 3 + 1] - cm[i1 * 3 + 1] + sy) * m;
        const float dz = (cm[i0 * 3 + 2] - cm[i1 * 3 + 2] + sz) * m;
        const float d = sqrtf(dx * dx + dy * dy + dz * dz + 1e-12f);
        float fc = 0.f;
        if (d < 5.0f)
            fc = 0.5f * (__cosf(0.62831853071795864769f * d) + 1.f) * m;  // pi/RC

        // tot_vec segment-sum (all valid pairs, independent of cutoff)
        atomicAdd(&tv[i0 * 3 + 0], dx);
        atomicAdd(&tv[i0 * 3 + 1], dy);
        atomicAdd(&tv[i0 * 3 + 2], dz);

        // ballot-compact the in-cutoff pairs into per-wave staging
        const unsigned long long mask = __ballot(fc > 0.f);
        const int pos = __builtin_amdgcn_mbcnt_hi((unsigned)(mask >> 32),
                        __builtin_amdgcn_mbcnt_lo((unsigned)mask, 0u));
        if (fc > 0.f) {
            __half2 hh = __floats2half2_rn(d, fc);
            s_df[wave][base + pos] = *reinterpret_cast<unsigned*>(&hh);
            s_pk[wave][base + pos] = (unsigned short)((i0 << 3) | sp[i1]);
        }
        base += __popcll(mask);

        // drain (counted loop, unroll x4, broadcast b128/b64 LDS reads)
        if (it == its - 1 || base > 128) {
            if (lane < 4) { s_df[wave][base + lane] = 0u; s_pk[wave][base + lane] = 0; }
            for (int k = 0; k < base; k += 4) {
                const uint4   df4 = *reinterpret_cast<const uint4*>(&s_df[wave][k]);
                const ushort4 pk4 = *reinterpret_cast<const ushort4*>(&s_pk[wave][k]);
                do_pair(df4.x, pk4.x, cb, wb, cemb, dens, lane);
                do_pair(df4.y, pk4.y, cb, wb, cemb, dens, lane);
                do_pair(df4.z, pk4.z, cb, wb, cemb, dens, lane);
                do_pair(df4.w, pk4.w, cb, wb, cemb, dens, lane);
            }
            base = 0;
        }
    }
    __syncthreads();

    // flush: PLAIN coalesced float4 stores into this block's private region
    float4* dg = reinterpret_cast<float4*>(dens_part + (size_t)blockIdx.x * NATOM * NB);
    const float4* ds4 = reinterpret_cast<const float4*>(dens);
    for (int i = tid; i < NATOM * NB / 4; i += 1024) dg[i] = ds4[i];
    float* tg = tv_part + (size_t)blockIdx.x * NATOM * 3;
    for (int i = tid; i < NATOM * 3; i += 1024) tg[i] = tv[i];
}

// ---------------------------------------------------------------------------
// reduce_kernel: sum nsub partials in place (into partial 0). Memory-bound.
// ---------------------------------------------------------------------------
__global__ __launch_bounds__(256) void reduce_kernel(float* dens_part, float* tv_part, int nsub)
{
    const int nd4 = NATOM * NB / 4;       // float4s per density partial-region
    const int nt  = NATOM * 3;            // floats per tv partial-region
    const int gid = blockIdx.x * 256 + threadIdx.x;
    const int nthreads = gridDim.x * 256;

    // density: region layout [mol*nsub + sub][NATOM*NB]
    for (int i = gid; i < NMOL * nd4; i += nthreads) {
        const int m  = i / nd4;
        const int e  = i - m * nd4;
        float4* base0 = reinterpret_cast<float4*>(dens_part + (size_t)m * nsub * NATOM * NB);
        float4 acc = base0[e];
        for (int s = 1; s < nsub; ++s) {
            const float4 v = base0[(size_t)s * nd4 + e];
            acc.x += v.x; acc.y += v.y; acc.z += v.z; acc.w += v.w;
        }
        base0[e] = acc;
    }
    for (int i = gid; i < NMOL * nt; i += nthreads) {
        const int m = i / nt;
        const int e = i - m * nt;
        float* base0 = tv_part + (size_t)m * nsub * NATOM * 3;
        float acc = base0[e];
        for (int s = 1; s < nsub; ++s) acc += base0[(size_t)s * nt + e];
        base0[e] = acc;
    }
}

// ---------------------------------------------------------------------------
// nn_kernel: 1024 blocks x 256 threads; block = 16 atoms, thread = hidden unit
// dens/tv row pointers take the molecule-strided (summed) partial-0 regions
// ---------------------------------------------------------------------------
__global__ __launch_bounds__(256) void nn_kernel(
    const float* __restrict__ dens_part, const float* __restrict__ tv_part,
    const float* __restrict__ W1, const float* __restrict__ b1,
    const float* __restrict__ W2, const float* __restrict__ b2,
    float* __restrict__ dipole, int nsub)
{
    const int j    = threadIdx.x;       // hidden unit 0..255
    const int lane = j & 63;
    const int wave = j >> 6;
    const int a0   = blockIdx.x * 16;                 // global atom base
    const int mol  = a0 / NATOM;
    const int arem = a0 - mol * NATOM;                // atom base within molecule
    const float* density = dens_part + (size_t)mol * nsub * NATOM * NB + (size_t)arem * NB;
    const float* totvec  = tv_part   + (size_t)mol * nsub * NATOM * 3  + (size_t)arem * 3;

    float w1r[64];
#pragma unroll
    for (int b = 0; b < 64; ++b) w1r[b] = W1[b * HIDDEN + j];
    const float b1v = b1[j];
    const float w2v = W2[j];

    float con[16];
#pragma unroll
    for (int a = 0; a < 16; ++a) {
        const float* row = density + a * NB;          // block-uniform -> s_load
        float h0 = b1v, h1 = 0.f, h2 = 0.f, h3 = 0.f;
#pragma unroll
        for (int b = 0; b < 64; b += 4) {
            h0 = fmaf(row[b + 0], w1r[b + 0], h0);
            h1 = fmaf(row[b + 1], w1r[b + 1], h1);
            h2 = fmaf(row[b + 2], w1r[b + 2], h2);
            h3 = fmaf(row[b + 3], w1r[b + 3], h3);
        }
        const float h = (h0 + h1) + (h2 + h3);
        con[a] = (h / (1.f + __expf(-h))) * w2v;      // silu * W2
    }

    __shared__ float part[4][16];
#pragma unroll
    for (int a = 0; a < 16; ++a) {
        float v = con[a];
#pragma unroll
        for (int off = 32; off; off >>= 1) v += __shfl_down(v, off);
        if (lane == 0) part[wave][a] = v;
    }
    __syncthreads();

    if (j < 16) {
        const int a = j;
        const float out = part[0][a] + part[1][a] + part[2][a] + part[3][a] + b2[0];
        const float* tvp = totvec + a * 3;
        float px = out * tvp[0], py = out * tvp[1], pz = out * tvp[2];
#pragma unroll
        for (int off = 8; off; off >>= 1) {
            px += __shfl_down(px, off, 16);
            py += __shfl_down(py, off, 16);
            pz += __shfl_down(pz, off, 16);
        }
        if (a == 0) {
            unsafeAtomicAdd(&dipole[mol * 3 + 0], px);
            unsafeAtomicAdd(&dipole[mol * 3 + 1], py);
            unsafeAtomicAdd(&dipole[mol * 3 + 2], pz);
        }
    }
}

// ---------------------------------------------------------------------------
extern "C" void kernel_launch(void* const* d_in, const int* in_sizes, int n_in,
                              void* d_out, int out_size, void* d_ws, size_t ws_size,
                              hipStream_t stream)
{
    const float* cart       = (const float*)d_in[0];
    const float* shifts     = (const float*)d_in[1];
    const float* centers    = (const float*)d_in[2];
    const float* widths     = (const float*)d_in[3];
    const float* c_emb      = (const float*)d_in[4];
    const float* W1         = (const float*)d_in[5];
    const float* b1         = (const float*)d_in[6];
    const float* W2         = (const float*)d_in[7];
    const float* b2         = (const float*)d_in[8];
    const int*   species    = (const int*)d_in[10];
    const int*   atom_index = (const int*)d_in[11];

    // pick the largest sub-split whose partials fit in the workspace
    int nsub = 8;
    while (nsub > 1 &&
           (size_t)nsub * TOTNATOM * (NB + 3) * sizeof(float) > ws_size) nsub >>= 1;

    float* dens_part = (float*)d_ws;                                  // [NMOL*nsub][NATOM*NB]
    float* tv_part   = dens_part + (size_t)NMOL * nsub * NATOM * NB;  // [NMOL*nsub][NATOM*3]
    float* dipole    = (float*)d_out;                                 // [32][3]

    hipMemsetAsync(d_out, 0, (size_t)out_size * sizeof(float), stream);

    hipLaunchKernelGGL(pair_kernel, dim3(NMOL * nsub), dim3(1024), 0, stream,
                       cart, shifts, centers, widths, c_emb, species, atom_index,
                       dens_part, tv_part, nsub);
    hipLaunchKernelGGL(reduce_kernel, dim3(1024), dim3(256), 0, stream,
                       dens_part, tv_part, nsub);
    hipLaunchKernelGGL(nn_kernel, dim3(TOTNATOM / 16), dim3(256), 0, stream,
                       dens_part, tv_part, W1, b1, W2, b2, dipole, nsub);
}